// Round 15
// baseline (127.745 us; speedup 1.0000x reference)
//
#include <hip/hip_runtime.h>
#include <math.h>

#define B_ 4096
#define Q_ 1024
#define KD 256
#define N_ 16384
#define F_ 512

typedef __attribute__((ext_vector_type(8))) short bhalf8;
typedef __attribute__((ext_vector_type(4))) float f32x4;
typedef __attribute__((ext_vector_type(16))) float f32x16;

static __device__ __forceinline__ unsigned short f2bf(float f) {
  unsigned int u = __builtin_bit_cast(unsigned int, f);
  unsigned int r = (u + 0x7fffu + ((u >> 16) & 1u)) >> 16;
  return (unsigned short)r;
}
static __device__ __forceinline__ float bf2f(unsigned short h) {
  return __builtin_bit_cast(float, (unsigned int)h << 16);
}
static __device__ __forceinline__ unsigned umaxu(unsigned a, unsigned b) { return a > b ? a : b; }
static __device__ __forceinline__ unsigned uminu(unsigned a, unsigned b) { return a < b ? a : b; }

// alpha-zero split: qproj_mfma zeroes bytes [0, 64MiB) (512 blk x 128KB,
// stores inside its BARRIER-FREE main loop -> drain only at kernel end);
// scores zeroes [64MiB, 256MiB) (1024 blk x 192KB, phases u<24).
#define QZ_BYTES 67108864

// ---------------------------------------------------------------------------
// k_prep (r13 verbatim): blocks [0,2048): keys fp32->bf16. [2048,3072):
// ph -> (ph_hi, ph_lo) split-bf16. [3072,3136): Wq -> wqT_{hi,lo}.
// ---------------------------------------------------------------------------
__global__ __launch_bounds__(256)
void k_prep(const float* __restrict__ keys, unsigned short* __restrict__ kbf,
            const float* __restrict__ ph, unsigned short* __restrict__ ph_hi,
            unsigned short* __restrict__ ph_lo,
            const float* __restrict__ Wq, unsigned short* __restrict__ wqT_hi,
            unsigned short* __restrict__ wqT_lo) {
  __shared__ float tile[64][65];
  const int tid = threadIdx.x;
  const int bid = blockIdx.x;

  if (bid < 2048) {  // ---- keys convert
    const size_t base = ((size_t)bid * 256 + tid) * 8;
    const float4 x = *reinterpret_cast<const float4*>(&keys[base]);
    const float4 y = *reinterpret_cast<const float4*>(&keys[base + 4]);
    bhalf8 o;
    o[0] = (short)f2bf(x.x); o[1] = (short)f2bf(x.y);
    o[2] = (short)f2bf(x.z); o[3] = (short)f2bf(x.w);
    o[4] = (short)f2bf(y.x); o[5] = (short)f2bf(y.y);
    o[6] = (short)f2bf(y.z); o[7] = (short)f2bf(y.w);
    *reinterpret_cast<bhalf8*>(&kbf[base]) = o;
    return;
  }
  if (bid < 3072) {  // ---- ph split: 16 elems/thread
    const size_t base = ((size_t)(bid - 2048) * 256 + tid) * 16;
    float v[16];
#pragma unroll
    for (int i = 0; i < 4; ++i) {
      const float4 x = *reinterpret_cast<const float4*>(&ph[base + i * 4]);
      v[i * 4 + 0] = x.x; v[i * 4 + 1] = x.y; v[i * 4 + 2] = x.z; v[i * 4 + 3] = x.w;
    }
    bhalf8 h0, h1, l0, l1;
#pragma unroll
    for (int i = 0; i < 16; ++i) {
      const unsigned short h = f2bf(v[i]);
      const unsigned short l = f2bf(v[i] - bf2f(h));
      if (i < 8) { h0[i] = (short)h; l0[i] = (short)l; }
      else       { h1[i - 8] = (short)h; l1[i - 8] = (short)l; }
    }
    *reinterpret_cast<bhalf8*>(&ph_hi[base]) = h0;
    *reinterpret_cast<bhalf8*>(&ph_hi[base + 8]) = h1;
    *reinterpret_cast<bhalf8*>(&ph_lo[base]) = l0;
    *reinterpret_cast<bhalf8*>(&ph_lo[base + 8]) = l1;
    return;
  }
  // ---- wqT transpose+split: 64 blocks, 64k x 64c tiles
  const int b = bid - 3072;
  const int k0 = (b >> 2) * 64, c0 = (b & 3) * 64;
  {
    const int kk = tid >> 2;
    const int cg = (tid & 3) * 16;
#pragma unroll
    for (int i = 0; i < 4; ++i) {
      const float4 x =
          *reinterpret_cast<const float4*>(&Wq[(size_t)(k0 + kk) * KD + c0 + cg + i * 4]);
      tile[kk][cg + i * 4 + 0] = x.x; tile[kk][cg + i * 4 + 1] = x.y;
      tile[kk][cg + i * 4 + 2] = x.z; tile[kk][cg + i * 4 + 3] = x.w;
    }
  }
  __syncthreads();
  {
    const int cc = tid >> 2;
    const int kg = (tid & 3) * 16;
    bhalf8 h0, h1, l0, l1;
#pragma unroll
    for (int i = 0; i < 16; ++i) {
      const float v = tile[kg + i][cc];
      const unsigned short h = f2bf(v);
      const unsigned short l = f2bf(v - bf2f(h));
      if (i < 8) { h0[i] = (short)h; l0[i] = (short)l; }
      else       { h1[i - 8] = (short)h; l1[i - 8] = (short)l; }
    }
    const size_t o = (size_t)(c0 + cc) * Q_ + k0 + kg;
    *reinterpret_cast<bhalf8*>(&wqT_hi[o]) = h0;
    *reinterpret_cast<bhalf8*>(&wqT_hi[o + 8]) = h1;
    *reinterpret_cast<bhalf8*>(&wqT_lo[o]) = l0;
    *reinterpret_cast<bhalf8*>(&wqT_lo[o + 8]) = l1;
  }
}

// ---------------------------------------------------------------------------
// k_qproj_mfma (r13 + alpha-zero share): q = ph@Wq + bq via split-bf16 3-pass
// MFMA. Main loop is BARRIER-FREE -> the 2 f4-stores/thread/iter (128KB/block,
// 64MiB over 512 blocks) drain only at the single final barrier / kernel end
// (r12's failure mode — per-chunk barrier drains — does not apply here).
// ---------------------------------------------------------------------------
__global__ __launch_bounds__(256)
void k_qproj_mfma(const unsigned short* __restrict__ ph_hi,
                  const unsigned short* __restrict__ ph_lo,
                  const unsigned short* __restrict__ wqT_hi,
                  const unsigned short* __restrict__ wqT_lo,
                  const float* __restrict__ bq, float* __restrict__ q,
                  unsigned short* __restrict__ qbf,
                  float* __restrict__ outAlpha) {
  __shared__ float red[4][32][64];   // 32 KB
  const int tid = threadIdx.x;
  const int wave = tid >> 6, lane = tid & 63;
  const int l31 = lane & 31, lhi = lane >> 5;
  const int c0 = blockIdx.x * 64;
  const int r0 = blockIdx.y * 32;
  const int k0 = wave * 256;
  const int qb = blockIdx.y * 4 + blockIdx.x;   // 0..511
  float4* zq = reinterpret_cast<float4*>((char*)outAlpha + (size_t)qb * 131072);
  const float4 z4 = {0.f, 0.f, 0.f, 0.f};

  const unsigned short* pa_h = ph_hi + (size_t)(r0 + l31) * Q_ + k0 + lhi * 8;
  const unsigned short* pa_l = ph_lo + (size_t)(r0 + l31) * Q_ + k0 + lhi * 8;
  const unsigned short* pb0_h = wqT_hi + (size_t)(c0 + l31) * Q_ + k0 + lhi * 8;
  const unsigned short* pb0_l = wqT_lo + (size_t)(c0 + l31) * Q_ + k0 + lhi * 8;
  const unsigned short* pb1_h = wqT_hi + (size_t)(c0 + 32 + l31) * Q_ + k0 + lhi * 8;
  const unsigned short* pb1_l = wqT_lo + (size_t)(c0 + 32 + l31) * Q_ + k0 + lhi * 8;

  f32x16 acc0 = {}, acc1 = {};
#pragma unroll
  for (int s = 0; s < 16; ++s) {
    const int ko = s * 16;
    // alpha-zero share: 2 f4-stores/thread/iter, no barrier in this loop
    zq[s * 512 + tid] = z4;
    zq[s * 512 + 256 + tid] = z4;
    const bhalf8 ah = *reinterpret_cast<const bhalf8*>(pa_h + ko);
    const bhalf8 al = *reinterpret_cast<const bhalf8*>(pa_l + ko);
    const bhalf8 b0h = *reinterpret_cast<const bhalf8*>(pb0_h + ko);
    const bhalf8 b0l = *reinterpret_cast<const bhalf8*>(pb0_l + ko);
    const bhalf8 b1h = *reinterpret_cast<const bhalf8*>(pb1_h + ko);
    const bhalf8 b1l = *reinterpret_cast<const bhalf8*>(pb1_l + ko);
    acc0 = __builtin_amdgcn_mfma_f32_32x32x16_bf16(ah, b0h, acc0, 0, 0, 0);
    acc0 = __builtin_amdgcn_mfma_f32_32x32x16_bf16(ah, b0l, acc0, 0, 0, 0);
    acc0 = __builtin_amdgcn_mfma_f32_32x32x16_bf16(al, b0h, acc0, 0, 0, 0);
    acc1 = __builtin_amdgcn_mfma_f32_32x32x16_bf16(ah, b1h, acc1, 0, 0, 0);
    acc1 = __builtin_amdgcn_mfma_f32_32x32x16_bf16(ah, b1l, acc1, 0, 0, 0);
    acc1 = __builtin_amdgcn_mfma_f32_32x32x16_bf16(al, b1h, acc1, 0, 0, 0);
  }

#pragma unroll
  for (int r = 0; r < 16; ++r) {
    const int rl = (r & 3) + 8 * (r >> 2) + 4 * lhi;
    red[wave][rl][l31] = acc0[r];
    red[wave][rl][32 + l31] = acc1[r];
  }
  __syncthreads();
  {
    const int rr = tid >> 3, cb = (tid & 7) * 8;
    float s[8] = {};
#pragma unroll
    for (int w = 0; w < 4; ++w) {
      const float4 t0 = *reinterpret_cast<const float4*>(&red[w][rr][cb]);
      const float4 t1 = *reinterpret_cast<const float4*>(&red[w][rr][cb + 4]);
      s[0] += t0.x; s[1] += t0.y; s[2] += t0.z; s[3] += t0.w;
      s[4] += t1.x; s[5] += t1.y; s[6] += t1.z; s[7] += t1.w;
    }
    const float4 b0 = *reinterpret_cast<const float4*>(&bq[c0 + cb]);
    const float4 b1 = *reinterpret_cast<const float4*>(&bq[c0 + cb + 4]);
    s[0] += b0.x; s[1] += b0.y; s[2] += b0.z; s[3] += b0.w;
    s[4] += b1.x; s[5] += b1.y; s[6] += b1.z; s[7] += b1.w;
    const size_t o = (size_t)(r0 + rr) * KD + c0 + cb;
    float4 o0, o1;
    o0.x = s[0]; o0.y = s[1]; o0.z = s[2]; o0.w = s[3];
    o1.x = s[4]; o1.y = s[5]; o1.z = s[6]; o1.w = s[7];
    *reinterpret_cast<float4*>(&q[o]) = o0;
    *reinterpret_cast<float4*>(&q[o + 4]) = o1;
    bhalf8 bv;
#pragma unroll
    for (int j = 0; j < 8; ++j) bv[j] = (short)f2bf(s[j]);
    *reinterpret_cast<bhalf8*>(&qbf[o]) = bv;
  }
}

// ---------------------------------------------------------------------------
// k_scores_mfma (r11 core): 32x32x16 MFMA + branchless packed top-2 per lane
// + zeroing of a 192KB alpha slice (phases u<24; qproj_mfma covers the first
// 64MiB). Block (bc,br): rows [br*64,+64) x cols [bc*1024,+1024). 4 blk/CU.
// ---------------------------------------------------------------------------
__global__ __launch_bounds__(256, 4)
void k_scores_mfma(const unsigned short* __restrict__ qbf,
                   const unsigned short* __restrict__ kbf,
                   unsigned* __restrict__ candP, float* __restrict__ outAlpha) {
  __shared__ __align__(16) char lds[32768];   // 2 x 16KB key tiles (64c x 128k)
  __shared__ unsigned mbuf[64 * 8];
  const int tid = threadIdx.x;
  const int wave = tid >> 6, lane = tid & 63;
  const int l31 = lane & 31, lhi = lane >> 5;
  const int rh = wave >> 1, ch = wave & 1;
  const int bc = blockIdx.x, br = blockIdx.y;
  const int row0 = br * 64;
  const int m_row = row0 + rh * 32 + l31;

  float4* zb = reinterpret_cast<float4*>(
      (char*)outAlpha + QZ_BYTES + (size_t)(br * 16 + bc) * 196608);
  const float4 z4 = {0.f, 0.f, 0.f, 0.f};

  bhalf8 qf[16];
#pragma unroll
  for (int kt = 0; kt < 16; ++kt)
    qf[kt] = *reinterpret_cast<const bhalf8*>(&qbf[(size_t)m_row * KD + kt * 16 + lhi * 8]);

  auto stage = [&](int bi, int u) {
    const int t = u >> 1, kh = u & 1;
#pragma unroll
    for (int i = 0; i < 4; ++i) {
      const int D = i * 4096 + tid * 16;
      const int colt = D >> 8;                 // 0..63
      const int kb = D & 255;
      const int kbs = kb ^ ((colt & 15) << 4);
      const char* src = (const char*)kbf +
          ((size_t)(bc * 1024 + t * 64 + colt) * 512 + kh * 256 + kbs);
      __builtin_amdgcn_global_load_lds(
          (const __attribute__((address_space(1))) unsigned int*)src,
          (__attribute__((address_space(3))) unsigned int*)(lds + bi * 16384 + D),
          16, 0, 0);
    }
  };

  unsigned P1 = 0u, P2 = 0u;            // packed top-2, descending
  const int acol = ch * 32 + l31;       // col within 64-col tile (A-operand row)
  const int swz = (acol & 15) << 4;
  const int kofs = lhi * 16;            // A k-offset bytes (8 bf16)

  stage(0, 0);
  __syncthreads();

  int buf = 0;
  for (int t = 0; t < 16; ++t) {
    f32x16 acc = {};
#pragma unroll
    for (int kh = 0; kh < 2; ++kh) {
      const int u = t * 2 + kh;
      if (u < 31) stage(buf ^ 1, u + 1);
      if (u < 24) {  // alpha-zero share: 2 stores/thread/phase (192KB total)
        zb[u * 512 + tid] = z4;
        zb[u * 512 + 256 + tid] = z4;
      }
      const char* kb = lds + buf * 16384 + acol * 256;
#pragma unroll
      for (int kt = 0; kt < 8; ++kt) {
        const bhalf8 af = *reinterpret_cast<const bhalf8*>(kb + ((kt * 32 + kofs) ^ swz));
        acc = __builtin_amdgcn_mfma_f32_32x32x16_bf16(af, qf[kh * 8 + kt], acc, 0, 0, 0);
      }
      if (kh == 1) {
        const int cb = t * 64 + ch * 32 + lhi * 4;
#pragma unroll
        for (int r = 0; r < 16; ++r) {
          const int rofs = (r & 3) + 8 * (r >> 2);
          const unsigned p =
              (__builtin_bit_cast(unsigned, acc[r] + 512.f) & 0xFFFFF800u) |
              (unsigned)(cb + rofs);
          const unsigned w1 = uminu(P1, p);
          P1 = umaxu(P1, p);
          P2 = umaxu(P2, w1);
        }
      }
      __syncthreads();
      buf ^= 1;
    }
  }

  // ---- block merge: per row 4 slots x 2 -> top-4 -> global candP
  {
    const int mrow = rh * 32 + l31;
    const int slot = ch * 2 + lhi;
    mbuf[mrow * 8 + slot * 2 + 0] = P1;
    mbuf[mrow * 8 + slot * 2 + 1] = P2;
  }
  __syncthreads();
  if (tid < 64) {
    unsigned T1 = 0u, T2 = 0u, T3 = 0u, T4 = 0u;
#pragma unroll
    for (int j = 0; j < 8; ++j) {
      const unsigned p = mbuf[tid * 8 + j];
      const unsigned w1 = uminu(T1, p); T1 = umaxu(T1, p);
      const unsigned w2 = uminu(T2, w1); T2 = umaxu(T2, w1);
      const unsigned w3 = uminu(T3, w2); T3 = umaxu(T3, w2);
      T4 = umaxu(T4, w3);
    }
    const size_t o = (size_t)(row0 + tid) * 64 + bc * 4;
    candP[o + 0] = T1; candP[o + 1] = T2; candP[o + 2] = T3; candP[o + 3] = T4;
  }
}

// ---------------------------------------------------------------------------
// k_finalize (r13 verbatim): one block per row. Top-8 of 64 packed cands,
// exact fp32 rescore, top-2 -> softmax -> scatter alpha + emb mix * beta.
// ---------------------------------------------------------------------------
__global__ __launch_bounds__(256)
void k_finalize(const float* __restrict__ q, const float* __restrict__ keys,
                const float* __restrict__ ph, const float* __restrict__ Wb,
                const float* __restrict__ bb, const float* __restrict__ embs,
                const unsigned* __restrict__ candP,
                float* __restrict__ outEmb, float* __restrict__ outAlpha) {
  __shared__ float red[4];
  __shared__ int   topIdx[8];
  __shared__ float resc[8];
  __shared__ float sParam[3];  // a1, a2, beta
  __shared__ int   sIdx[2];
  const int tid = threadIdx.x;
  const int wave = tid >> 6, lane = tid & 63;
  const int row = blockIdx.x;
  float* arow = outAlpha + (size_t)row * N_;

  {
    const float4 a = *reinterpret_cast<const float4*>(&ph[(size_t)row * Q_ + tid * 4]);
    const float4 w = *reinterpret_cast<const float4*>(&Wb[tid * 4]);
    float s = a.x * w.x + a.y * w.y + a.z * w.z + a.w * w.w;
#pragma unroll
    for (int m = 32; m >= 1; m >>= 1) s += __shfl_xor(s, m);
    if (lane == 0) red[wave] = s;
  }

  if (wave == 0) {
    unsigned p = candP[(size_t)row * 64 + lane];
    const int mycol = (lane >> 2) * 1024 + (int)(p & 0x7FFu);
#pragma unroll
    for (int it = 0; it < 8; ++it) {
      unsigned mx = p;
#pragma unroll
      for (int m = 32; m >= 1; m >>= 1) {
        const unsigned o = (unsigned)__shfl_xor((int)mx, m);
        mx = mx > o ? mx : o;
      }
      const unsigned long long bal = __ballot(p == mx);
      const int src = __ffsll((unsigned long long)bal) - 1;
      if (lane == src) { topIdx[it] = mycol; p = 0u; }
    }
  }
  __syncthreads();

  {
#pragma unroll
    for (int h = 0; h < 2; ++h) {
      const int cnd = topIdx[wave * 2 + h];
      const float4 qv = *reinterpret_cast<const float4*>(&q[(size_t)row * KD + lane * 4]);
      const float4 kv = *reinterpret_cast<const float4*>(&keys[(size_t)cnd * KD + lane * 4]);
      float s = qv.x * kv.x + qv.y * kv.y + qv.z * kv.z + qv.w * kv.w;
#pragma unroll
      for (int m = 32; m >= 1; m >>= 1) s += __shfl_xor(s, m);
      if (lane == 0) resc[wave * 2 + h] = s * 0.0625f;
    }
  }
  __syncthreads();

  if (tid == 0) {
    float w1 = -INFINITY, w2 = -INFINITY; int j1 = 0x7fffffff, j2 = 0x7fffffff;
#pragma unroll
    for (int c = 0; c < 8; ++c) {
      const float v = resc[c]; const int x = topIdx[c];
      const bool beat1 = (v > w1) || (v == w1 && x < j1);
      const bool beat2 = (v > w2) || (v == w2 && x < j2);
      if (beat1) { w2 = w1; j2 = j1; w1 = v; j1 = x; }
      else if (beat2) { w2 = v; j2 = x; }
    }
    const float t = expf(w2 - w1);
    const float inv = 1.f / (1.f + t);
    const float bsum = red[0] + red[1] + red[2] + red[3] + bb[0];
    sParam[0] = inv; sParam[1] = t * inv;
    sParam[2] = 1.f / (1.f + expf(-bsum));
    sIdx[0] = j1; sIdx[1] = j2;
  }
  __syncthreads();

  const float a1 = sParam[0], a2 = sParam[1], beta = sParam[2];
  const int j1 = sIdx[0], j2 = sIdx[1];
  if (tid == 0) { arow[j1] = a1; arow[j2] = a2; }
  if (tid < 128) {
    const int f = tid * 4;
    const float4 e1 = *reinterpret_cast<const float4*>(&embs[(size_t)j1 * F_ + f]);
    const float4 e2 = *reinterpret_cast<const float4*>(&embs[(size_t)j2 * F_ + f]);
    float4 o;
    o.x = beta * (a1 * e1.x + a2 * e2.x);
    o.y = beta * (a1 * e1.y + a2 * e2.y);
    o.z = beta * (a1 * e1.z + a2 * e2.z);
    o.w = beta * (a1 * e1.w + a2 * e2.w);
    *reinterpret_cast<float4*>(&outEmb[(size_t)row * F_ + f]) = o;
  }
}

// ---------------------------------------------------------------------------
extern "C" void kernel_launch(void* const* d_in, const int* in_sizes, int n_in,
                              void* d_out, int out_size, void* d_ws, size_t ws_size,
                              hipStream_t stream) {
  const float* ph   = (const float*)d_in[0];
  const float* keys = (const float*)d_in[1];
  const float* embs = (const float*)d_in[2];
  const float* Wq   = (const float*)d_in[3];
  const float* bq   = (const float*)d_in[4];
  const float* Wb   = (const float*)d_in[5];
  const float* bb   = (const float*)d_in[6];

  float* outEmb   = (float*)d_out;
  float* outAlpha = outEmb + (size_t)B_ * F_;

  // workspace (~32 MB)
  float*          q      = (float*)d_ws;                                  // 4 MB
  unsigned short* qbf    = (unsigned short*)(q + (size_t)B_ * KD);        // 2 MB
  unsigned short* kbf    = qbf + (size_t)B_ * KD;                         // 8 MB
  unsigned*       candP  = (unsigned*)(kbf + (size_t)N_ * KD);            // 1 MB
  unsigned short* ph_hi  = (unsigned short*)(candP + (size_t)B_ * 64);    // 8 MB
  unsigned short* ph_lo  = ph_hi + (size_t)B_ * Q_;                       // 8 MB
  unsigned short* wqT_hi = ph_lo + (size_t)B_ * Q_;                       // 0.5 MB
  unsigned short* wqT_lo = wqT_hi + (size_t)KD * Q_;                      // 0.5 MB

  k_prep<<<3136, 256, 0, stream>>>(keys, kbf, ph, ph_hi, ph_lo, Wq, wqT_hi, wqT_lo);
  k_qproj_mfma<<<dim3(4, 128), 256, 0, stream>>>(ph_hi, ph_lo, wqT_hi, wqT_lo,
                                                 bq, q, qbf, outAlpha);
  k_scores_mfma<<<dim3(16, 64), 256, 0, stream>>>(qbf, kbf, candP, outAlpha);
  k_finalize<<<B_, 256, 0, stream>>>(q, keys, ph, Wb, bb, embs, candP,
                                     outEmb, outAlpha);
}

// Round 16
// 124.938 us; speedup vs baseline: 1.0225x; 1.0225x over previous
//
#include <hip/hip_runtime.h>
#include <math.h>

#define B_ 4096
#define Q_ 1024
#define KD 256
#define N_ 16384
#define F_ 512

typedef __attribute__((ext_vector_type(8))) short bhalf8;
typedef __attribute__((ext_vector_type(4))) float f32x4;
typedef __attribute__((ext_vector_type(16))) float f32x16;

static __device__ __forceinline__ unsigned short f2bf(float f) {
  unsigned int u = __builtin_bit_cast(unsigned int, f);
  unsigned int r = (u + 0x7fffu + ((u >> 16) & 1u)) >> 16;
  return (unsigned short)r;
}
static __device__ __forceinline__ float bf2f(unsigned short h) {
  return __builtin_bit_cast(float, (unsigned int)h << 16);
}
static __device__ __forceinline__ unsigned umaxu(unsigned a, unsigned b) { return a > b ? a : b; }
static __device__ __forceinline__ unsigned uminu(unsigned a, unsigned b) { return a < b ? a : b; }

// ---------------------------------------------------------------------------
// k_prep: blocks [0,1024): ph -> (ph_hi, ph_lo) split-bf16.
// [1024,1088): Wq -> wqT_{hi,lo} transpose+split.
// (keys convert moved into k_qproj_mfma's launch — kbf is only needed by
// scores, so it can overlap the q projection.)
// ---------------------------------------------------------------------------
__global__ __launch_bounds__(256)
void k_prep(const float* __restrict__ ph, unsigned short* __restrict__ ph_hi,
            unsigned short* __restrict__ ph_lo,
            const float* __restrict__ Wq, unsigned short* __restrict__ wqT_hi,
            unsigned short* __restrict__ wqT_lo) {
  __shared__ float tile[64][65];
  const int tid = threadIdx.x;
  const int bid = blockIdx.x;

  if (bid < 1024) {  // ---- ph split: 16 elems/thread
    const size_t base = ((size_t)bid * 256 + tid) * 16;
    float v[16];
#pragma unroll
    for (int i = 0; i < 4; ++i) {
      const float4 x = *reinterpret_cast<const float4*>(&ph[base + i * 4]);
      v[i * 4 + 0] = x.x; v[i * 4 + 1] = x.y; v[i * 4 + 2] = x.z; v[i * 4 + 3] = x.w;
    }
    bhalf8 h0, h1, l0, l1;
#pragma unroll
    for (int i = 0; i < 16; ++i) {
      const unsigned short h = f2bf(v[i]);
      const unsigned short l = f2bf(v[i] - bf2f(h));
      if (i < 8) { h0[i] = (short)h; l0[i] = (short)l; }
      else       { h1[i - 8] = (short)h; l1[i - 8] = (short)l; }
    }
    *reinterpret_cast<bhalf8*>(&ph_hi[base]) = h0;
    *reinterpret_cast<bhalf8*>(&ph_hi[base + 8]) = h1;
    *reinterpret_cast<bhalf8*>(&ph_lo[base]) = l0;
    *reinterpret_cast<bhalf8*>(&ph_lo[base + 8]) = l1;
    return;
  }
  // ---- wqT transpose+split: 64 blocks, 64k x 64c tiles
  const int b = bid - 1024;
  const int k0 = (b >> 2) * 64, c0 = (b & 3) * 64;
  {
    const int kk = tid >> 2;
    const int cg = (tid & 3) * 16;
#pragma unroll
    for (int i = 0; i < 4; ++i) {
      const float4 x =
          *reinterpret_cast<const float4*>(&Wq[(size_t)(k0 + kk) * KD + c0 + cg + i * 4]);
      tile[kk][cg + i * 4 + 0] = x.x; tile[kk][cg + i * 4 + 1] = x.y;
      tile[kk][cg + i * 4 + 2] = x.z; tile[kk][cg + i * 4 + 3] = x.w;
    }
  }
  __syncthreads();
  {
    const int cc = tid >> 2;
    const int kg = (tid & 3) * 16;
    bhalf8 h0, h1, l0, l1;
#pragma unroll
    for (int i = 0; i < 16; ++i) {
      const float v = tile[kg + i][cc];
      const unsigned short h = f2bf(v);
      const unsigned short l = f2bf(v - bf2f(h));
      if (i < 8) { h0[i] = (short)h; l0[i] = (short)l; }
      else       { h1[i - 8] = (short)h; l1[i - 8] = (short)l; }
    }
    const size_t o = (size_t)(c0 + cc) * Q_ + k0 + kg;
    *reinterpret_cast<bhalf8*>(&wqT_hi[o]) = h0;
    *reinterpret_cast<bhalf8*>(&wqT_hi[o + 8]) = h1;
    *reinterpret_cast<bhalf8*>(&wqT_lo[o]) = l0;
    *reinterpret_cast<bhalf8*>(&wqT_lo[o + 8]) = l1;
  }
}

// ---------------------------------------------------------------------------
// k_qproj_mfma (r13 core + trailing keys-convert blocks): q = ph@Wq + bq via
// split-bf16 3-pass MFMA (hi*hi + hi*lo + lo*hi).
// Blocks [0,512): MFMA (flattened r13 grid: c0=(bid&3)*64, r0=(bid>>2)*32) —
// dispatched FIRST so they fill all CUs (2/CU); blocks [512,2560): keys
// fp32->bf16 streaming convert backfills as MFMA blocks retire (kbf is only
// needed by the NEXT kernel). Inverse of r4's failure ordering.
// ---------------------------------------------------------------------------
__global__ __launch_bounds__(256)
void k_qproj_mfma(const unsigned short* __restrict__ ph_hi,
                  const unsigned short* __restrict__ ph_lo,
                  const unsigned short* __restrict__ wqT_hi,
                  const unsigned short* __restrict__ wqT_lo,
                  const float* __restrict__ bq, float* __restrict__ q,
                  unsigned short* __restrict__ qbf,
                  const float* __restrict__ keys,
                  unsigned short* __restrict__ kbf) {
  __shared__ float red[4][32][64];   // 32 KB
  const int tid = threadIdx.x;
  const int bid = blockIdx.x;

  if (bid >= 512) {  // ---- keys convert: 8 elems/thread
    const size_t base = ((size_t)(bid - 512) * 256 + tid) * 8;
    const float4 x = *reinterpret_cast<const float4*>(&keys[base]);
    const float4 y = *reinterpret_cast<const float4*>(&keys[base + 4]);
    bhalf8 o;
    o[0] = (short)f2bf(x.x); o[1] = (short)f2bf(x.y);
    o[2] = (short)f2bf(x.z); o[3] = (short)f2bf(x.w);
    o[4] = (short)f2bf(y.x); o[5] = (short)f2bf(y.y);
    o[6] = (short)f2bf(y.z); o[7] = (short)f2bf(y.w);
    *reinterpret_cast<bhalf8*>(&kbf[base]) = o;
    return;
  }

  const int wave = tid >> 6, lane = tid & 63;
  const int l31 = lane & 31, lhi = lane >> 5;
  const int c0 = (bid & 3) * 64;
  const int r0 = (bid >> 2) * 32;
  const int k0 = wave * 256;

  const unsigned short* pa_h = ph_hi + (size_t)(r0 + l31) * Q_ + k0 + lhi * 8;
  const unsigned short* pa_l = ph_lo + (size_t)(r0 + l31) * Q_ + k0 + lhi * 8;
  const unsigned short* pb0_h = wqT_hi + (size_t)(c0 + l31) * Q_ + k0 + lhi * 8;
  const unsigned short* pb0_l = wqT_lo + (size_t)(c0 + l31) * Q_ + k0 + lhi * 8;
  const unsigned short* pb1_h = wqT_hi + (size_t)(c0 + 32 + l31) * Q_ + k0 + lhi * 8;
  const unsigned short* pb1_l = wqT_lo + (size_t)(c0 + 32 + l31) * Q_ + k0 + lhi * 8;

  f32x16 acc0 = {}, acc1 = {};
#pragma unroll
  for (int s = 0; s < 16; ++s) {
    const int ko = s * 16;
    const bhalf8 ah = *reinterpret_cast<const bhalf8*>(pa_h + ko);
    const bhalf8 al = *reinterpret_cast<const bhalf8*>(pa_l + ko);
    const bhalf8 b0h = *reinterpret_cast<const bhalf8*>(pb0_h + ko);
    const bhalf8 b0l = *reinterpret_cast<const bhalf8*>(pb0_l + ko);
    const bhalf8 b1h = *reinterpret_cast<const bhalf8*>(pb1_h + ko);
    const bhalf8 b1l = *reinterpret_cast<const bhalf8*>(pb1_l + ko);
    acc0 = __builtin_amdgcn_mfma_f32_32x32x16_bf16(ah, b0h, acc0, 0, 0, 0);
    acc0 = __builtin_amdgcn_mfma_f32_32x32x16_bf16(ah, b0l, acc0, 0, 0, 0);
    acc0 = __builtin_amdgcn_mfma_f32_32x32x16_bf16(al, b0h, acc0, 0, 0, 0);
    acc1 = __builtin_amdgcn_mfma_f32_32x32x16_bf16(ah, b1h, acc1, 0, 0, 0);
    acc1 = __builtin_amdgcn_mfma_f32_32x32x16_bf16(ah, b1l, acc1, 0, 0, 0);
    acc1 = __builtin_amdgcn_mfma_f32_32x32x16_bf16(al, b1h, acc1, 0, 0, 0);
  }

#pragma unroll
  for (int r = 0; r < 16; ++r) {
    const int rl = (r & 3) + 8 * (r >> 2) + 4 * lhi;
    red[wave][rl][l31] = acc0[r];
    red[wave][rl][32 + l31] = acc1[r];
  }
  __syncthreads();
  {
    const int rr = tid >> 3, cb = (tid & 7) * 8;
    float s[8] = {};
#pragma unroll
    for (int w = 0; w < 4; ++w) {
      const float4 t0 = *reinterpret_cast<const float4*>(&red[w][rr][cb]);
      const float4 t1 = *reinterpret_cast<const float4*>(&red[w][rr][cb + 4]);
      s[0] += t0.x; s[1] += t0.y; s[2] += t0.z; s[3] += t0.w;
      s[4] += t1.x; s[5] += t1.y; s[6] += t1.z; s[7] += t1.w;
    }
    const float4 b0 = *reinterpret_cast<const float4*>(&bq[c0 + cb]);
    const float4 b1 = *reinterpret_cast<const float4*>(&bq[c0 + cb + 4]);
    s[0] += b0.x; s[1] += b0.y; s[2] += b0.z; s[3] += b0.w;
    s[4] += b1.x; s[5] += b1.y; s[6] += b1.z; s[7] += b1.w;
    const size_t o = (size_t)(r0 + rr) * KD + c0 + cb;
    float4 o0, o1;
    o0.x = s[0]; o0.y = s[1]; o0.z = s[2]; o0.w = s[3];
    o1.x = s[4]; o1.y = s[5]; o1.z = s[6]; o1.w = s[7];
    *reinterpret_cast<float4*>(&q[o]) = o0;
    *reinterpret_cast<float4*>(&q[o + 4]) = o1;
    bhalf8 bv;
#pragma unroll
    for (int j = 0; j < 8; ++j) bv[j] = (short)f2bf(s[j]);
    *reinterpret_cast<bhalf8*>(&qbf[o]) = bv;
  }
}

// ---------------------------------------------------------------------------
// k_scores_mfma (r13/r11 exact form): 32x32x16 MFMA + branchless packed
// top-2 per lane + interleaved zeroing of this block's FULL 256KB alpha slice
// (r12/r15 established: the zero belongs entirely here).
// Block (bc,br): rows [br*64,+64) x cols [bc*1024,+1024). 4 blocks/CU.
// ---------------------------------------------------------------------------
__global__ __launch_bounds__(256, 4)
void k_scores_mfma(const unsigned short* __restrict__ qbf,
                   const unsigned short* __restrict__ kbf,
                   unsigned* __restrict__ candP, float* __restrict__ outAlpha) {
  __shared__ __align__(16) char lds[32768];   // 2 x 16KB key tiles (64c x 128k)
  __shared__ unsigned mbuf[64 * 8];
  const int tid = threadIdx.x;
  const int wave = tid >> 6, lane = tid & 63;
  const int l31 = lane & 31, lhi = lane >> 5;
  const int rh = wave >> 1, ch = wave & 1;
  const int bc = blockIdx.x, br = blockIdx.y;
  const int row0 = br * 64;
  const int m_row = row0 + rh * 32 + l31;

  float4* zb = reinterpret_cast<float4*>(
      (char*)outAlpha + (size_t)(br * 16 + bc) * 262144);
  const float4 z4 = {0.f, 0.f, 0.f, 0.f};

  bhalf8 qf[16];
#pragma unroll
  for (int kt = 0; kt < 16; ++kt)
    qf[kt] = *reinterpret_cast<const bhalf8*>(&qbf[(size_t)m_row * KD + kt * 16 + lhi * 8]);

  auto stage = [&](int bi, int u) {
    const int t = u >> 1, kh = u & 1;
#pragma unroll
    for (int i = 0; i < 4; ++i) {
      const int D = i * 4096 + tid * 16;
      const int colt = D >> 8;                 // 0..63
      const int kb = D & 255;
      const int kbs = kb ^ ((colt & 15) << 4);
      const char* src = (const char*)kbf +
          ((size_t)(bc * 1024 + t * 64 + colt) * 512 + kh * 256 + kbs);
      __builtin_amdgcn_global_load_lds(
          (const __attribute__((address_space(1))) unsigned int*)src,
          (__attribute__((address_space(3))) unsigned int*)(lds + bi * 16384 + D),
          16, 0, 0);
    }
  };

  unsigned P1 = 0u, P2 = 0u;            // packed top-2, descending
  const int acol = ch * 32 + l31;       // col within 64-col tile (A-operand row)
  const int swz = (acol & 15) << 4;
  const int kofs = lhi * 16;            // A k-offset bytes (8 bf16)

  stage(0, 0);
  __syncthreads();

  int buf = 0;
  for (int t = 0; t < 16; ++t) {
    f32x16 acc = {};
#pragma unroll
    for (int kh = 0; kh < 2; ++kh) {
      const int u = t * 2 + kh;
      if (u < 31) stage(buf ^ 1, u + 1);
      // interleaved alpha zeroing: 2 stores/thread/phase, drains at barrier
      zb[u * 512 + tid] = z4;
      zb[u * 512 + 256 + tid] = z4;
      const char* kb = lds + buf * 16384 + acol * 256;
#pragma unroll
      for (int kt = 0; kt < 8; ++kt) {
        const bhalf8 af = *reinterpret_cast<const bhalf8*>(kb + ((kt * 32 + kofs) ^ swz));
        acc = __builtin_amdgcn_mfma_f32_32x32x16_bf16(af, qf[kh * 8 + kt], acc, 0, 0, 0);
      }
      if (kh == 1) {
        const int cb = t * 64 + ch * 32 + lhi * 4;
#pragma unroll
        for (int r = 0; r < 16; ++r) {
          const int rofs = (r & 3) + 8 * (r >> 2);
          const unsigned p =
              (__builtin_bit_cast(unsigned, acc[r] + 512.f) & 0xFFFFF800u) |
              (unsigned)(cb + rofs);
          const unsigned w1 = uminu(P1, p);
          P1 = umaxu(P1, p);
          P2 = umaxu(P2, w1);
        }
      }
      __syncthreads();
      buf ^= 1;
    }
  }

  // ---- block merge: per row 4 slots x 2 -> top-4 -> global candP
  {
    const int mrow = rh * 32 + l31;
    const int slot = ch * 2 + lhi;
    mbuf[mrow * 8 + slot * 2 + 0] = P1;
    mbuf[mrow * 8 + slot * 2 + 1] = P2;
  }
  __syncthreads();
  if (tid < 64) {
    unsigned T1 = 0u, T2 = 0u, T3 = 0u, T4 = 0u;
#pragma unroll
    for (int j = 0; j < 8; ++j) {
      const unsigned p = mbuf[tid * 8 + j];
      const unsigned w1 = uminu(T1, p); T1 = umaxu(T1, p);
      const unsigned w2 = uminu(T2, w1); T2 = umaxu(T2, w1);
      const unsigned w3 = uminu(T3, w2); T3 = umaxu(T3, w2);
      T4 = umaxu(T4, w3);
    }
    const size_t o = (size_t)(row0 + tid) * 64 + bc * 4;
    candP[o + 0] = T1; candP[o + 1] = T2; candP[o + 2] = T3; candP[o + 3] = T4;
  }
}

// ---------------------------------------------------------------------------
// k_finalize (r13 verbatim): one block per row. Top-8 of 64 packed cands,
// exact fp32 rescore, top-2 -> softmax -> scatter alpha + emb mix * beta.
// ---------------------------------------------------------------------------
__global__ __launch_bounds__(256)
void k_finalize(const float* __restrict__ q, const float* __restrict__ keys,
                const float* __restrict__ ph, const float* __restrict__ Wb,
                const float* __restrict__ bb, const float* __restrict__ embs,
                const unsigned* __restrict__ candP,
                float* __restrict__ outEmb, float* __restrict__ outAlpha) {
  __shared__ float red[4];
  __shared__ int   topIdx[8];
  __shared__ float resc[8];
  __shared__ float sParam[3];  // a1, a2, beta
  __shared__ int   sIdx[2];
  const int tid = threadIdx.x;
  const int wave = tid >> 6, lane = tid & 63;
  const int row = blockIdx.x;
  float* arow = outAlpha + (size_t)row * N_;

  {
    const float4 a = *reinterpret_cast<const float4*>(&ph[(size_t)row * Q_ + tid * 4]);
    const float4 w = *reinterpret_cast<const float4*>(&Wb[tid * 4]);
    float s = a.x * w.x + a.y * w.y + a.z * w.z + a.w * w.w;
#pragma unroll
    for (int m = 32; m >= 1; m >>= 1) s += __shfl_xor(s, m);
    if (lane == 0) red[wave] = s;
  }

  if (wave == 0) {
    unsigned p = candP[(size_t)row * 64 + lane];
    const int mycol = (lane >> 2) * 1024 + (int)(p & 0x7FFu);
#pragma unroll
    for (int it = 0; it < 8; ++it) {
      unsigned mx = p;
#pragma unroll
      for (int m = 32; m >= 1; m >>= 1) {
        const unsigned o = (unsigned)__shfl_xor((int)mx, m);
        mx = mx > o ? mx : o;
      }
      const unsigned long long bal = __ballot(p == mx);
      const int src = __ffsll((unsigned long long)bal) - 1;
      if (lane == src) { topIdx[it] = mycol; p = 0u; }
    }
  }
  __syncthreads();

  {
#pragma unroll
    for (int h = 0; h < 2; ++h) {
      const int cnd = topIdx[wave * 2 + h];
      const float4 qv = *reinterpret_cast<const float4*>(&q[(size_t)row * KD + lane * 4]);
      const float4 kv = *reinterpret_cast<const float4*>(&keys[(size_t)cnd * KD + lane * 4]);
      float s = qv.x * kv.x + qv.y * kv.y + qv.z * kv.z + qv.w * kv.w;
#pragma unroll
      for (int m = 32; m >= 1; m >>= 1) s += __shfl_xor(s, m);
      if (lane == 0) resc[wave * 2 + h] = s * 0.0625f;
    }
  }
  __syncthreads();

  if (tid == 0) {
    float w1 = -INFINITY, w2 = -INFINITY; int j1 = 0x7fffffff, j2 = 0x7fffffff;
#pragma unroll
    for (int c = 0; c < 8; ++c) {
      const float v = resc[c]; const int x = topIdx[c];
      const bool beat1 = (v > w1) || (v == w1 && x < j1);
      const bool beat2 = (v > w2) || (v == w2 && x < j2);
      if (beat1) { w2 = w1; j2 = j1; w1 = v; j1 = x; }
      else if (beat2) { w2 = v; j2 = x; }
    }
    const float t = expf(w2 - w1);
    const float inv = 1.f / (1.f + t);
    const float bsum = red[0] + red[1] + red[2] + red[3] + bb[0];
    sParam[0] = inv; sParam[1] = t * inv;
    sParam[2] = 1.f / (1.f + expf(-bsum));
    sIdx[0] = j1; sIdx[1] = j2;
  }
  __syncthreads();

  const float a1 = sParam[0], a2 = sParam[1], beta = sParam[2];
  const int j1 = sIdx[0], j2 = sIdx[1];
  if (tid == 0) { arow[j1] = a1; arow[j2] = a2; }
  if (tid < 128) {
    const int f = tid * 4;
    const float4 e1 = *reinterpret_cast<const float4*>(&embs[(size_t)j1 * F_ + f]);
    const float4 e2 = *reinterpret_cast<const float4*>(&embs[(size_t)j2 * F_ + f]);
    float4 o;
    o.x = beta * (a1 * e1.x + a2 * e2.x);
    o.y = beta * (a1 * e1.y + a2 * e2.y);
    o.z = beta * (a1 * e1.z + a2 * e2.z);
    o.w = beta * (a1 * e1.w + a2 * e2.w);
    *reinterpret_cast<float4*>(&outEmb[(size_t)row * F_ + f]) = o;
  }
}

// ---------------------------------------------------------------------------
extern "C" void kernel_launch(void* const* d_in, const int* in_sizes, int n_in,
                              void* d_out, int out_size, void* d_ws, size_t ws_size,
                              hipStream_t stream) {
  const float* ph   = (const float*)d_in[0];
  const float* keys = (const float*)d_in[1];
  const float* embs = (const float*)d_in[2];
  const float* Wq   = (const float*)d_in[3];
  const float* bq   = (const float*)d_in[4];
  const float* Wb   = (const float*)d_in[5];
  const float* bb   = (const float*)d_in[6];

  float* outEmb   = (float*)d_out;
  float* outAlpha = outEmb + (size_t)B_ * F_;

  // workspace (~32 MB)
  float*          q      = (float*)d_ws;                                  // 4 MB
  unsigned short* qbf    = (unsigned short*)(q + (size_t)B_ * KD);        // 2 MB
  unsigned short* kbf    = qbf + (size_t)B_ * KD;                         // 8 MB
  unsigned*       candP  = (unsigned*)(kbf + (size_t)N_ * KD);            // 1 MB
  unsigned short* ph_hi  = (unsigned short*)(candP + (size_t)B_ * 64);    // 8 MB
  unsigned short* ph_lo  = ph_hi + (size_t)B_ * Q_;                       // 8 MB
  unsigned short* wqT_hi = ph_lo + (size_t)B_ * Q_;                       // 0.5 MB
  unsigned short* wqT_lo = wqT_hi + (size_t)KD * Q_;                      // 0.5 MB

  k_prep<<<1088, 256, 0, stream>>>(ph, ph_hi, ph_lo, Wq, wqT_hi, wqT_lo);
  k_qproj_mfma<<<2560, 256, 0, stream>>>(ph_hi, ph_lo, wqT_hi, wqT_lo,
                                         bq, q, qbf, keys, kbf);
  k_scores_mfma<<<dim3(16, 64), 256, 0, stream>>>(qbf, kbf, candP, outAlpha);
  k_finalize<<<B_, 256, 0, stream>>>(q, keys, ph, Wb, bb, embs, candP,
                                     outEmb, outAlpha);
}

// Round 17
// 119.812 us; speedup vs baseline: 1.0662x; 1.0428x over previous
//
#include <hip/hip_runtime.h>
#include <math.h>

#define B_ 4096
#define Q_ 1024
#define KD 256
#define N_ 16384
#define F_ 512

typedef __attribute__((ext_vector_type(8))) short bhalf8;
typedef __attribute__((ext_vector_type(4))) float f32x4;
typedef __attribute__((ext_vector_type(16))) float f32x16;

static __device__ __forceinline__ unsigned short f2bf(float f) {
  unsigned int u = __builtin_bit_cast(unsigned int, f);
  unsigned int r = (u + 0x7fffu + ((u >> 16) & 1u)) >> 16;
  return (unsigned short)r;
}
static __device__ __forceinline__ float bf2f(unsigned short h) {
  return __builtin_bit_cast(float, (unsigned int)h << 16);
}
static __device__ __forceinline__ unsigned umaxu(unsigned a, unsigned b) { return a > b ? a : b; }
static __device__ __forceinline__ unsigned uminu(unsigned a, unsigned b) { return a < b ? a : b; }

// ---------------------------------------------------------------------------
// k_prep: ONLY Wq -> wqT_{hi,lo} transpose + split-bf16 now (64 blocks).
// The ph split moved in-register into k_qproj_mfma (saves 32MB HBM round-trip
// and 1024 prep blocks).
// ---------------------------------------------------------------------------
__global__ __launch_bounds__(256)
void k_prep(const float* __restrict__ Wq, unsigned short* __restrict__ wqT_hi,
            unsigned short* __restrict__ wqT_lo) {
  __shared__ float tile[64][65];
  const int tid = threadIdx.x;
  const int b = blockIdx.x;
  const int k0 = (b >> 2) * 64, c0 = (b & 3) * 64;
  {
    const int kk = tid >> 2;
    const int cg = (tid & 3) * 16;
#pragma unroll
    for (int i = 0; i < 4; ++i) {
      const float4 x =
          *reinterpret_cast<const float4*>(&Wq[(size_t)(k0 + kk) * KD + c0 + cg + i * 4]);
      tile[kk][cg + i * 4 + 0] = x.x; tile[kk][cg + i * 4 + 1] = x.y;
      tile[kk][cg + i * 4 + 2] = x.z; tile[kk][cg + i * 4 + 3] = x.w;
    }
  }
  __syncthreads();
  {
    const int cc = tid >> 2;
    const int kg = (tid & 3) * 16;
    bhalf8 h0, h1, l0, l1;
#pragma unroll
    for (int i = 0; i < 16; ++i) {
      const float v = tile[kg + i][cc];
      const unsigned short h = f2bf(v);
      const unsigned short l = f2bf(v - bf2f(h));
      if (i < 8) { h0[i] = (short)h; l0[i] = (short)l; }
      else       { h1[i - 8] = (short)h; l1[i - 8] = (short)l; }
    }
    const size_t o = (size_t)(c0 + cc) * Q_ + k0 + kg;
    *reinterpret_cast<bhalf8*>(&wqT_hi[o]) = h0;
    *reinterpret_cast<bhalf8*>(&wqT_hi[o + 8]) = h1;
    *reinterpret_cast<bhalf8*>(&wqT_lo[o]) = l0;
    *reinterpret_cast<bhalf8*>(&wqT_lo[o + 8]) = l1;
  }
}

// ---------------------------------------------------------------------------
// k_qproj_mfma: q = ph@Wq + bq via split-bf16 3-pass MFMA, with the ph
// hi/lo split done IN-REGISTER from fp32 ph (same 32B/lane read as the old
// hi+lo pair; kills prep's 32MB materialization). VALU split (~50cyc/iter)
// overlaps the MFMA pipe. Blocks [0,512): MFMA (c0=(bid&3)*64,
// r0=(bid>>2)*32); blocks [512,2560): keys fp32->bf16 convert backfill.
// ---------------------------------------------------------------------------
__global__ __launch_bounds__(256)
void k_qproj_mfma(const float* __restrict__ ph,
                  const unsigned short* __restrict__ wqT_hi,
                  const unsigned short* __restrict__ wqT_lo,
                  const float* __restrict__ bq, float* __restrict__ q,
                  unsigned short* __restrict__ qbf,
                  const float* __restrict__ keys,
                  unsigned short* __restrict__ kbf) {
  __shared__ float red[4][32][64];   // 32 KB
  const int tid = threadIdx.x;
  const int bid = blockIdx.x;

  if (bid >= 512) {  // ---- keys convert: 8 elems/thread
    const size_t base = ((size_t)(bid - 512) * 256 + tid) * 8;
    const float4 x = *reinterpret_cast<const float4*>(&keys[base]);
    const float4 y = *reinterpret_cast<const float4*>(&keys[base + 4]);
    bhalf8 o;
    o[0] = (short)f2bf(x.x); o[1] = (short)f2bf(x.y);
    o[2] = (short)f2bf(x.z); o[3] = (short)f2bf(x.w);
    o[4] = (short)f2bf(y.x); o[5] = (short)f2bf(y.y);
    o[6] = (short)f2bf(y.z); o[7] = (short)f2bf(y.w);
    *reinterpret_cast<bhalf8*>(&kbf[base]) = o;
    return;
  }

  const int wave = tid >> 6, lane = tid & 63;
  const int l31 = lane & 31, lhi = lane >> 5;
  const int c0 = (bid & 3) * 64;
  const int r0 = (bid >> 2) * 32;
  const int k0 = wave * 256;

  const float* pa = ph + (size_t)(r0 + l31) * Q_ + k0 + lhi * 8;
  const unsigned short* pb0_h = wqT_hi + (size_t)(c0 + l31) * Q_ + k0 + lhi * 8;
  const unsigned short* pb0_l = wqT_lo + (size_t)(c0 + l31) * Q_ + k0 + lhi * 8;
  const unsigned short* pb1_h = wqT_hi + (size_t)(c0 + 32 + l31) * Q_ + k0 + lhi * 8;
  const unsigned short* pb1_l = wqT_lo + (size_t)(c0 + 32 + l31) * Q_ + k0 + lhi * 8;

  f32x16 acc0 = {}, acc1 = {};
#pragma unroll
  for (int s = 0; s < 16; ++s) {
    const int ko = s * 16;
    // in-register ph split: 8 contiguous fp32 -> bf16 hi + bf16 lo
    const float4 va = *reinterpret_cast<const float4*>(pa + ko);
    const float4 vb = *reinterpret_cast<const float4*>(pa + ko + 4);
    float v[8];
    v[0] = va.x; v[1] = va.y; v[2] = va.z; v[3] = va.w;
    v[4] = vb.x; v[5] = vb.y; v[6] = vb.z; v[7] = vb.w;
    bhalf8 ah, al;
#pragma unroll
    for (int j = 0; j < 8; ++j) {
      const unsigned short h = f2bf(v[j]);
      ah[j] = (short)h;
      al[j] = (short)f2bf(v[j] - bf2f(h));
    }
    const bhalf8 b0h = *reinterpret_cast<const bhalf8*>(pb0_h + ko);
    const bhalf8 b0l = *reinterpret_cast<const bhalf8*>(pb0_l + ko);
    const bhalf8 b1h = *reinterpret_cast<const bhalf8*>(pb1_h + ko);
    const bhalf8 b1l = *reinterpret_cast<const bhalf8*>(pb1_l + ko);
    acc0 = __builtin_amdgcn_mfma_f32_32x32x16_bf16(ah, b0h, acc0, 0, 0, 0);
    acc0 = __builtin_amdgcn_mfma_f32_32x32x16_bf16(ah, b0l, acc0, 0, 0, 0);
    acc0 = __builtin_amdgcn_mfma_f32_32x32x16_bf16(al, b0h, acc0, 0, 0, 0);
    acc1 = __builtin_amdgcn_mfma_f32_32x32x16_bf16(ah, b1h, acc1, 0, 0, 0);
    acc1 = __builtin_amdgcn_mfma_f32_32x32x16_bf16(ah, b1l, acc1, 0, 0, 0);
    acc1 = __builtin_amdgcn_mfma_f32_32x32x16_bf16(al, b1h, acc1, 0, 0, 0);
  }

#pragma unroll
  for (int r = 0; r < 16; ++r) {
    const int rl = (r & 3) + 8 * (r >> 2) + 4 * lhi;
    red[wave][rl][l31] = acc0[r];
    red[wave][rl][32 + l31] = acc1[r];
  }
  __syncthreads();
  {
    const int rr = tid >> 3, cb = (tid & 7) * 8;
    float s[8] = {};
#pragma unroll
    for (int w = 0; w < 4; ++w) {
      const float4 t0 = *reinterpret_cast<const float4*>(&red[w][rr][cb]);
      const float4 t1 = *reinterpret_cast<const float4*>(&red[w][rr][cb + 4]);
      s[0] += t0.x; s[1] += t0.y; s[2] += t0.z; s[3] += t0.w;
      s[4] += t1.x; s[5] += t1.y; s[6] += t1.z; s[7] += t1.w;
    }
    const float4 b0 = *reinterpret_cast<const float4*>(&bq[c0 + cb]);
    const float4 b1 = *reinterpret_cast<const float4*>(&bq[c0 + cb + 4]);
    s[0] += b0.x; s[1] += b0.y; s[2] += b0.z; s[3] += b0.w;
    s[4] += b1.x; s[5] += b1.y; s[6] += b1.z; s[7] += b1.w;
    const size_t o = (size_t)(r0 + rr) * KD + c0 + cb;
    float4 o0, o1;
    o0.x = s[0]; o0.y = s[1]; o0.z = s[2]; o0.w = s[3];
    o1.x = s[4]; o1.y = s[5]; o1.z = s[6]; o1.w = s[7];
    *reinterpret_cast<float4*>(&q[o]) = o0;
    *reinterpret_cast<float4*>(&q[o + 4]) = o1;
    bhalf8 bv;
#pragma unroll
    for (int j = 0; j < 8; ++j) bv[j] = (short)f2bf(s[j]);
    *reinterpret_cast<bhalf8*>(&qbf[o]) = bv;
  }
}

// ---------------------------------------------------------------------------
// k_scores_mfma (r16 verbatim): 32x32x16 MFMA + branchless packed top-2 per
// lane + interleaved zeroing of this block's FULL 256KB alpha slice.
// Block (bc,br): rows [br*64,+64) x cols [bc*1024,+1024). 4 blocks/CU.
// ---------------------------------------------------------------------------
__global__ __launch_bounds__(256, 4)
void k_scores_mfma(const unsigned short* __restrict__ qbf,
                   const unsigned short* __restrict__ kbf,
                   unsigned* __restrict__ candP, float* __restrict__ outAlpha) {
  __shared__ __align__(16) char lds[32768];   // 2 x 16KB key tiles (64c x 128k)
  __shared__ unsigned mbuf[64 * 8];
  const int tid = threadIdx.x;
  const int wave = tid >> 6, lane = tid & 63;
  const int l31 = lane & 31, lhi = lane >> 5;
  const int rh = wave >> 1, ch = wave & 1;
  const int bc = blockIdx.x, br = blockIdx.y;
  const int row0 = br * 64;
  const int m_row = row0 + rh * 32 + l31;

  float4* zb = reinterpret_cast<float4*>(
      (char*)outAlpha + (size_t)(br * 16 + bc) * 262144);
  const float4 z4 = {0.f, 0.f, 0.f, 0.f};

  bhalf8 qf[16];
#pragma unroll
  for (int kt = 0; kt < 16; ++kt)
    qf[kt] = *reinterpret_cast<const bhalf8*>(&qbf[(size_t)m_row * KD + kt * 16 + lhi * 8]);

  auto stage = [&](int bi, int u) {
    const int t = u >> 1, kh = u & 1;
#pragma unroll
    for (int i = 0; i < 4; ++i) {
      const int D = i * 4096 + tid * 16;
      const int colt = D >> 8;                 // 0..63
      const int kb = D & 255;
      const int kbs = kb ^ ((colt & 15) << 4);
      const char* src = (const char*)kbf +
          ((size_t)(bc * 1024 + t * 64 + colt) * 512 + kh * 256 + kbs);
      __builtin_amdgcn_global_load_lds(
          (const __attribute__((address_space(1))) unsigned int*)src,
          (__attribute__((address_space(3))) unsigned int*)(lds + bi * 16384 + D),
          16, 0, 0);
    }
  };

  unsigned P1 = 0u, P2 = 0u;            // packed top-2, descending
  const int acol = ch * 32 + l31;       // col within 64-col tile (A-operand row)
  const int swz = (acol & 15) << 4;
  const int kofs = lhi * 16;            // A k-offset bytes (8 bf16)

  stage(0, 0);
  __syncthreads();

  int buf = 0;
  for (int t = 0; t < 16; ++t) {
    f32x16 acc = {};
#pragma unroll
    for (int kh = 0; kh < 2; ++kh) {
      const int u = t * 2 + kh;
      if (u < 31) stage(buf ^ 1, u + 1);
      // interleaved alpha zeroing: 2 stores/thread/phase, drains at barrier
      zb[u * 512 + tid] = z4;
      zb[u * 512 + 256 + tid] = z4;
      const char* kb = lds + buf * 16384 + acol * 256;
#pragma unroll
      for (int kt = 0; kt < 8; ++kt) {
        const bhalf8 af = *reinterpret_cast<const bhalf8*>(kb + ((kt * 32 + kofs) ^ swz));
        acc = __builtin_amdgcn_mfma_f32_32x32x16_bf16(af, qf[kh * 8 + kt], acc, 0, 0, 0);
      }
      if (kh == 1) {
        const int cb = t * 64 + ch * 32 + lhi * 4;
#pragma unroll
        for (int r = 0; r < 16; ++r) {
          const int rofs = (r & 3) + 8 * (r >> 2);
          const unsigned p =
              (__builtin_bit_cast(unsigned, acc[r] + 512.f) & 0xFFFFF800u) |
              (unsigned)(cb + rofs);
          const unsigned w1 = uminu(P1, p);
          P1 = umaxu(P1, p);
          P2 = umaxu(P2, w1);
        }
      }
      __syncthreads();
      buf ^= 1;
    }
  }

  // ---- block merge: per row 4 slots x 2 -> top-4 -> global candP
  {
    const int mrow = rh * 32 + l31;
    const int slot = ch * 2 + lhi;
    mbuf[mrow * 8 + slot * 2 + 0] = P1;
    mbuf[mrow * 8 + slot * 2 + 1] = P2;
  }
  __syncthreads();
  if (tid < 64) {
    unsigned T1 = 0u, T2 = 0u, T3 = 0u, T4 = 0u;
#pragma unroll
    for (int j = 0; j < 8; ++j) {
      const unsigned p = mbuf[tid * 8 + j];
      const unsigned w1 = uminu(T1, p); T1 = umaxu(T1, p);
      const unsigned w2 = uminu(T2, w1); T2 = umaxu(T2, w1);
      const unsigned w3 = uminu(T3, w2); T3 = umaxu(T3, w2);
      T4 = umaxu(T4, w3);
    }
    const size_t o = (size_t)(row0 + tid) * 64 + bc * 4;
    candP[o + 0] = T1; candP[o + 1] = T2; candP[o + 2] = T3; candP[o + 3] = T4;
  }
}

// ---------------------------------------------------------------------------
// k_finalize (r13 verbatim): one block per row. Top-8 of 64 packed cands,
// exact fp32 rescore, top-2 -> softmax -> scatter alpha + emb mix * beta.
// ---------------------------------------------------------------------------
__global__ __launch_bounds__(256)
void k_finalize(const float* __restrict__ q, const float* __restrict__ keys,
                const float* __restrict__ ph, const float* __restrict__ Wb,
                const float* __restrict__ bb, const float* __restrict__ embs,
                const unsigned* __restrict__ candP,
                float* __restrict__ outEmb, float* __restrict__ outAlpha) {
  __shared__ float red[4];
  __shared__ int   topIdx[8];
  __shared__ float resc[8];
  __shared__ float sParam[3];  // a1, a2, beta
  __shared__ int   sIdx[2];
  const int tid = threadIdx.x;
  const int wave = tid >> 6, lane = tid & 63;
  const int row = blockIdx.x;
  float* arow = outAlpha + (size_t)row * N_;

  {
    const float4 a = *reinterpret_cast<const float4*>(&ph[(size_t)row * Q_ + tid * 4]);
    const float4 w = *reinterpret_cast<const float4*>(&Wb[tid * 4]);
    float s = a.x * w.x + a.y * w.y + a.z * w.z + a.w * w.w;
#pragma unroll
    for (int m = 32; m >= 1; m >>= 1) s += __shfl_xor(s, m);
    if (lane == 0) red[wave] = s;
  }

  if (wave == 0) {
    unsigned p = candP[(size_t)row * 64 + lane];
    const int mycol = (lane >> 2) * 1024 + (int)(p & 0x7FFu);
#pragma unroll
    for (int it = 0; it < 8; ++it) {
      unsigned mx = p;
#pragma unroll
      for (int m = 32; m >= 1; m >>= 1) {
        const unsigned o = (unsigned)__shfl_xor((int)mx, m);
        mx = mx > o ? mx : o;
      }
      const unsigned long long bal = __ballot(p == mx);
      const int src = __ffsll((unsigned long long)bal) - 1;
      if (lane == src) { topIdx[it] = mycol; p = 0u; }
    }
  }
  __syncthreads();

  {
#pragma unroll
    for (int h = 0; h < 2; ++h) {
      const int cnd = topIdx[wave * 2 + h];
      const float4 qv = *reinterpret_cast<const float4*>(&q[(size_t)row * KD + lane * 4]);
      const float4 kv = *reinterpret_cast<const float4*>(&keys[(size_t)cnd * KD + lane * 4]);
      float s = qv.x * kv.x + qv.y * kv.y + qv.z * kv.z + qv.w * kv.w;
#pragma unroll
      for (int m = 32; m >= 1; m >>= 1) s += __shfl_xor(s, m);
      if (lane == 0) resc[wave * 2 + h] = s * 0.0625f;
    }
  }
  __syncthreads();

  if (tid == 0) {
    float w1 = -INFINITY, w2 = -INFINITY; int j1 = 0x7fffffff, j2 = 0x7fffffff;
#pragma unroll
    for (int c = 0; c < 8; ++c) {
      const float v = resc[c]; const int x = topIdx[c];
      const bool beat1 = (v > w1) || (v == w1 && x < j1);
      const bool beat2 = (v > w2) || (v == w2 && x < j2);
      if (beat1) { w2 = w1; j2 = j1; w1 = v; j1 = x; }
      else if (beat2) { w2 = v; j2 = x; }
    }
    const float t = expf(w2 - w1);
    const float inv = 1.f / (1.f + t);
    const float bsum = red[0] + red[1] + red[2] + red[3] + bb[0];
    sParam[0] = inv; sParam[1] = t * inv;
    sParam[2] = 1.f / (1.f + expf(-bsum));
    sIdx[0] = j1; sIdx[1] = j2;
  }
  __syncthreads();

  const float a1 = sParam[0], a2 = sParam[1], beta = sParam[2];
  const int j1 = sIdx[0], j2 = sIdx[1];
  if (tid == 0) { arow[j1] = a1; arow[j2] = a2; }
  if (tid < 128) {
    const int f = tid * 4;
    const float4 e1 = *reinterpret_cast<const float4*>(&embs[(size_t)j1 * F_ + f]);
    const float4 e2 = *reinterpret_cast<const float4*>(&embs[(size_t)j2 * F_ + f]);
    float4 o;
    o.x = beta * (a1 * e1.x + a2 * e2.x);
    o.y = beta * (a1 * e1.y + a2 * e2.y);
    o.z = beta * (a1 * e1.z + a2 * e2.z);
    o.w = beta * (a1 * e1.w + a2 * e2.w);
    *reinterpret_cast<float4*>(&outEmb[(size_t)row * F_ + f]) = o;
  }
}

// ---------------------------------------------------------------------------
extern "C" void kernel_launch(void* const* d_in, const int* in_sizes, int n_in,
                              void* d_out, int out_size, void* d_ws, size_t ws_size,
                              hipStream_t stream) {
  const float* ph   = (const float*)d_in[0];
  const float* keys = (const float*)d_in[1];
  const float* embs = (const float*)d_in[2];
  const float* Wq   = (const float*)d_in[3];
  const float* bq   = (const float*)d_in[4];
  const float* Wb   = (const float*)d_in[5];
  const float* bb   = (const float*)d_in[6];

  float* outEmb   = (float*)d_out;
  float* outAlpha = outEmb + (size_t)B_ * F_;

  // workspace (~16 MB)
  float*          q      = (float*)d_ws;                                  // 4 MB
  unsigned short* qbf    = (unsigned short*)(q + (size_t)B_ * KD);        // 2 MB
  unsigned short* kbf    = qbf + (size_t)B_ * KD;                         // 8 MB
  unsigned*       candP  = (unsigned*)(kbf + (size_t)N_ * KD);            // 1 MB
  unsigned short* wqT_hi = (unsigned short*)(candP + (size_t)B_ * 64);    // 0.5 MB
  unsigned short* wqT_lo = wqT_hi + (size_t)KD * Q_;                      // 0.5 MB

  k_prep<<<64, 256, 0, stream>>>(Wq, wqT_hi, wqT_lo);
  k_qproj_mfma<<<2560, 256, 0, stream>>>(ph, wqT_hi, wqT_lo, bq, q, qbf,
                                         keys, kbf);
  k_scores_mfma<<<dim3(16, 64), 256, 0, stream>>>(qbf, kbf, candP, outAlpha);
  k_finalize<<<B_, 256, 0, stream>>>(q, keys, ph, Wb, bb, embs, candP,
                                     outEmb, outAlpha);
}

// Round 18
// 119.481 us; speedup vs baseline: 1.0692x; 1.0028x over previous
//
#include <hip/hip_runtime.h>
#include <math.h>

#define B_ 4096
#define Q_ 1024
#define KD 256
#define N_ 16384
#define F_ 512

typedef __attribute__((ext_vector_type(8))) short bhalf8;
typedef __attribute__((ext_vector_type(4))) float f32x4;
typedef __attribute__((ext_vector_type(16))) float f32x16;

static __device__ __forceinline__ unsigned short f2bf(float f) {
  unsigned int u = __builtin_bit_cast(unsigned int, f);
  unsigned int r = (u + 0x7fffu + ((u >> 16) & 1u)) >> 16;
  return (unsigned short)r;
}
static __device__ __forceinline__ float bf2f(unsigned short h) {
  return __builtin_bit_cast(float, (unsigned int)h << 16);
}
static __device__ __forceinline__ unsigned umaxu(unsigned a, unsigned b) { return a > b ? a : b; }
static __device__ __forceinline__ unsigned uminu(unsigned a, unsigned b) { return a < b ? a : b; }

// alpha-zero split (per ROW): scores zeroes cols [0,12288) of every row
// (192MB, hideable under its ~32us compute); finalize zeroes its OWN row's
// tail cols [12288,16384) (16KB/block, 64MB) before scattering (block-local
// ordering via __syncthreads vmcnt drain -> no race).

// ---------------------------------------------------------------------------
// k_prep: blocks [0,64): Wq -> wqT_{hi,lo} transpose+split.
// blocks [64,1088): beta = sigmoid(ph·Wb + bb), one wave per row.
// ---------------------------------------------------------------------------
__global__ __launch_bounds__(256)
void k_prep(const float* __restrict__ Wq, unsigned short* __restrict__ wqT_hi,
            unsigned short* __restrict__ wqT_lo,
            const float* __restrict__ ph, const float* __restrict__ Wb,
            const float* __restrict__ bb, float* __restrict__ betaArr) {
  __shared__ float tile[64][65];
  const int tid = threadIdx.x;
  const int bid = blockIdx.x;

  if (bid >= 64) {  // ---- beta: wave w handles row (bid-64)*4 + w
    const int lane = tid & 63, wave = tid >> 6;
    const int row = (bid - 64) * 4 + wave;
    float s = 0.f;
#pragma unroll
    for (int i = 0; i < 4; ++i) {
      const float4 a = *reinterpret_cast<const float4*>(&ph[(size_t)row * Q_ + lane * 4 + i * 256]);
      const float4 w = *reinterpret_cast<const float4*>(&Wb[lane * 4 + i * 256]);
      s += a.x * w.x + a.y * w.y + a.z * w.z + a.w * w.w;
    }
#pragma unroll
    for (int m = 32; m >= 1; m >>= 1) s += __shfl_xor(s, m);
    if (lane == 0) betaArr[row] = 1.f / (1.f + expf(-(s + bb[0])));
    return;
  }

  // ---- wqT transpose+split: 64 blocks, 64k x 64c tiles
  const int b = bid;
  const int k0 = (b >> 2) * 64, c0 = (b & 3) * 64;
  {
    const int kk = tid >> 2;
    const int cg = (tid & 3) * 16;
#pragma unroll
    for (int i = 0; i < 4; ++i) {
      const float4 x =
          *reinterpret_cast<const float4*>(&Wq[(size_t)(k0 + kk) * KD + c0 + cg + i * 4]);
      tile[kk][cg + i * 4 + 0] = x.x; tile[kk][cg + i * 4 + 1] = x.y;
      tile[kk][cg + i * 4 + 2] = x.z; tile[kk][cg + i * 4 + 3] = x.w;
    }
  }
  __syncthreads();
  {
    const int cc = tid >> 2;
    const int kg = (tid & 3) * 16;
    bhalf8 h0, h1, l0, l1;
#pragma unroll
    for (int i = 0; i < 16; ++i) {
      const float v = tile[kg + i][cc];
      const unsigned short h = f2bf(v);
      const unsigned short l = f2bf(v - bf2f(h));
      if (i < 8) { h0[i] = (short)h; l0[i] = (short)l; }
      else       { h1[i - 8] = (short)h; l1[i - 8] = (short)l; }
    }
    const size_t o = (size_t)(c0 + cc) * Q_ + k0 + kg;
    *reinterpret_cast<bhalf8*>(&wqT_hi[o]) = h0;
    *reinterpret_cast<bhalf8*>(&wqT_hi[o + 8]) = h1;
    *reinterpret_cast<bhalf8*>(&wqT_lo[o]) = l0;
    *reinterpret_cast<bhalf8*>(&wqT_lo[o + 8]) = l1;
  }
}

// ---------------------------------------------------------------------------
// k_qproj_mfma (r17 verbatim): q = ph@Wq + bq via split-bf16 3-pass MFMA with
// in-register ph hi/lo split. Blocks [0,512): MFMA; [512,2560): keys convert.
// ---------------------------------------------------------------------------
__global__ __launch_bounds__(256)
void k_qproj_mfma(const float* __restrict__ ph,
                  const unsigned short* __restrict__ wqT_hi,
                  const unsigned short* __restrict__ wqT_lo,
                  const float* __restrict__ bq, float* __restrict__ q,
                  unsigned short* __restrict__ qbf,
                  const float* __restrict__ keys,
                  unsigned short* __restrict__ kbf) {
  __shared__ float red[4][32][64];   // 32 KB
  const int tid = threadIdx.x;
  const int bid = blockIdx.x;

  if (bid >= 512) {  // ---- keys convert: 8 elems/thread
    const size_t base = ((size_t)(bid - 512) * 256 + tid) * 8;
    const float4 x = *reinterpret_cast<const float4*>(&keys[base]);
    const float4 y = *reinterpret_cast<const float4*>(&keys[base + 4]);
    bhalf8 o;
    o[0] = (short)f2bf(x.x); o[1] = (short)f2bf(x.y);
    o[2] = (short)f2bf(x.z); o[3] = (short)f2bf(x.w);
    o[4] = (short)f2bf(y.x); o[5] = (short)f2bf(y.y);
    o[6] = (short)f2bf(y.z); o[7] = (short)f2bf(y.w);
    *reinterpret_cast<bhalf8*>(&kbf[base]) = o;
    return;
  }

  const int wave = tid >> 6, lane = tid & 63;
  const int l31 = lane & 31, lhi = lane >> 5;
  const int c0 = (bid & 3) * 64;
  const int r0 = (bid >> 2) * 32;
  const int k0 = wave * 256;

  const float* pa = ph + (size_t)(r0 + l31) * Q_ + k0 + lhi * 8;
  const unsigned short* pb0_h = wqT_hi + (size_t)(c0 + l31) * Q_ + k0 + lhi * 8;
  const unsigned short* pb0_l = wqT_lo + (size_t)(c0 + l31) * Q_ + k0 + lhi * 8;
  const unsigned short* pb1_h = wqT_hi + (size_t)(c0 + 32 + l31) * Q_ + k0 + lhi * 8;
  const unsigned short* pb1_l = wqT_lo + (size_t)(c0 + 32 + l31) * Q_ + k0 + lhi * 8;

  f32x16 acc0 = {}, acc1 = {};
#pragma unroll
  for (int s = 0; s < 16; ++s) {
    const int ko = s * 16;
    const float4 va = *reinterpret_cast<const float4*>(pa + ko);
    const float4 vb = *reinterpret_cast<const float4*>(pa + ko + 4);
    float v[8];
    v[0] = va.x; v[1] = va.y; v[2] = va.z; v[3] = va.w;
    v[4] = vb.x; v[5] = vb.y; v[6] = vb.z; v[7] = vb.w;
    bhalf8 ah, al;
#pragma unroll
    for (int j = 0; j < 8; ++j) {
      const unsigned short h = f2bf(v[j]);
      ah[j] = (short)h;
      al[j] = (short)f2bf(v[j] - bf2f(h));
    }
    const bhalf8 b0h = *reinterpret_cast<const bhalf8*>(pb0_h + ko);
    const bhalf8 b0l = *reinterpret_cast<const bhalf8*>(pb0_l + ko);
    const bhalf8 b1h = *reinterpret_cast<const bhalf8*>(pb1_h + ko);
    const bhalf8 b1l = *reinterpret_cast<const bhalf8*>(pb1_l + ko);
    acc0 = __builtin_amdgcn_mfma_f32_32x32x16_bf16(ah, b0h, acc0, 0, 0, 0);
    acc0 = __builtin_amdgcn_mfma_f32_32x32x16_bf16(ah, b0l, acc0, 0, 0, 0);
    acc0 = __builtin_amdgcn_mfma_f32_32x32x16_bf16(al, b0h, acc0, 0, 0, 0);
    acc1 = __builtin_amdgcn_mfma_f32_32x32x16_bf16(ah, b1h, acc1, 0, 0, 0);
    acc1 = __builtin_amdgcn_mfma_f32_32x32x16_bf16(ah, b1l, acc1, 0, 0, 0);
    acc1 = __builtin_amdgcn_mfma_f32_32x32x16_bf16(al, b1h, acc1, 0, 0, 0);
  }

#pragma unroll
  for (int r = 0; r < 16; ++r) {
    const int rl = (r & 3) + 8 * (r >> 2) + 4 * lhi;
    red[wave][rl][l31] = acc0[r];
    red[wave][rl][32 + l31] = acc1[r];
  }
  __syncthreads();
  {
    const int rr = tid >> 3, cb = (tid & 7) * 8;
    float s[8] = {};
#pragma unroll
    for (int w = 0; w < 4; ++w) {
      const float4 t0 = *reinterpret_cast<const float4*>(&red[w][rr][cb]);
      const float4 t1 = *reinterpret_cast<const float4*>(&red[w][rr][cb + 4]);
      s[0] += t0.x; s[1] += t0.y; s[2] += t0.z; s[3] += t0.w;
      s[4] += t1.x; s[5] += t1.y; s[6] += t1.z; s[7] += t1.w;
    }
    const float4 b0 = *reinterpret_cast<const float4*>(&bq[c0 + cb]);
    const float4 b1 = *reinterpret_cast<const float4*>(&bq[c0 + cb + 4]);
    s[0] += b0.x; s[1] += b0.y; s[2] += b0.z; s[3] += b0.w;
    s[4] += b1.x; s[5] += b1.y; s[6] += b1.z; s[7] += b1.w;
    const size_t o = (size_t)(r0 + rr) * KD + c0 + cb;
    float4 o0, o1;
    o0.x = s[0]; o0.y = s[1]; o0.z = s[2]; o0.w = s[3];
    o1.x = s[4]; o1.y = s[5]; o1.z = s[6]; o1.w = s[7];
    *reinterpret_cast<float4*>(&q[o]) = o0;
    *reinterpret_cast<float4*>(&q[o + 4]) = o1;
    bhalf8 bv;
#pragma unroll
    for (int j = 0; j < 8; ++j) bv[j] = (short)f2bf(s[j]);
    *reinterpret_cast<bhalf8*>(&qbf[o]) = bv;
  }
}

// ---------------------------------------------------------------------------
// k_scores_mfma: 32x32x16 MFMA + branchless packed top-2 per lane + zeroing
// of the FRONT region (cols [0,12288)) of its 4 rows (192KB/block, phases
// u<24; finalize zeroes each row's tail). 4 blocks/CU.
// ---------------------------------------------------------------------------
__global__ __launch_bounds__(256, 4)
void k_scores_mfma(const unsigned short* __restrict__ qbf,
                   const unsigned short* __restrict__ kbf,
                   unsigned* __restrict__ candP, float* __restrict__ outAlpha) {
  __shared__ __align__(16) char lds[32768];   // 2 x 16KB key tiles (64c x 128k)
  __shared__ unsigned mbuf[64 * 8];
  const int tid = threadIdx.x;
  const int wave = tid >> 6, lane = tid & 63;
  const int l31 = lane & 31, lhi = lane >> 5;
  const int rh = wave >> 1, ch = wave & 1;
  const int bc = blockIdx.x, br = blockIdx.y;
  const int row0 = br * 64;
  const int m_row = row0 + rh * 32 + l31;

  // front-zero: 4 rows starting at (br*16+bc)*4; per row f4 [0,3072)
  float4* zb = reinterpret_cast<float4*>(outAlpha) + (size_t)(br * 16 + bc) * 16384;
  const float4 z4 = {0.f, 0.f, 0.f, 0.f};

  bhalf8 qf[16];
#pragma unroll
  for (int kt = 0; kt < 16; ++kt)
    qf[kt] = *reinterpret_cast<const bhalf8*>(&qbf[(size_t)m_row * KD + kt * 16 + lhi * 8]);

  auto stage = [&](int bi, int u) {
    const int t = u >> 1, kh = u & 1;
#pragma unroll
    for (int i = 0; i < 4; ++i) {
      const int D = i * 4096 + tid * 16;
      const int colt = D >> 8;                 // 0..63
      const int kb = D & 255;
      const int kbs = kb ^ ((colt & 15) << 4);
      const char* src = (const char*)kbf +
          ((size_t)(bc * 1024 + t * 64 + colt) * 512 + kh * 256 + kbs);
      __builtin_amdgcn_global_load_lds(
          (const __attribute__((address_space(1))) unsigned int*)src,
          (__attribute__((address_space(3))) unsigned int*)(lds + bi * 16384 + D),
          16, 0, 0);
    }
  };

  unsigned P1 = 0u, P2 = 0u;            // packed top-2, descending
  const int acol = ch * 32 + l31;       // col within 64-col tile (A-operand row)
  const int swz = (acol & 15) << 4;
  const int kofs = lhi * 16;            // A k-offset bytes (8 bf16)

  stage(0, 0);
  __syncthreads();

  int buf = 0;
  for (int t = 0; t < 16; ++t) {
    f32x16 acc = {};
#pragma unroll
    for (int kh = 0; kh < 2; ++kh) {
      const int u = t * 2 + kh;
      if (u < 31) stage(buf ^ 1, u + 1);
      if (u < 24) {  // front-zero: row u/6, 8KB chunk u%6
        const int rsel = u / 6, csel = u - rsel * 6;
        float4* z = zb + rsel * 4096 + csel * 512;
        z[tid] = z4;
        z[256 + tid] = z4;
      }
      const char* kb = lds + buf * 16384 + acol * 256;
#pragma unroll
      for (int kt = 0; kt < 8; ++kt) {
        const bhalf8 af = *reinterpret_cast<const bhalf8*>(kb + ((kt * 32 + kofs) ^ swz));
        acc = __builtin_amdgcn_mfma_f32_32x32x16_bf16(af, qf[kh * 8 + kt], acc, 0, 0, 0);
      }
      if (kh == 1) {
        const int cb = t * 64 + ch * 32 + lhi * 4;
#pragma unroll
        for (int r = 0; r < 16; ++r) {
          const int rofs = (r & 3) + 8 * (r >> 2);
          const unsigned p =
              (__builtin_bit_cast(unsigned, acc[r] + 512.f) & 0xFFFFF800u) |
              (unsigned)(cb + rofs);
          const unsigned w1 = uminu(P1, p);
          P1 = umaxu(P1, p);
          P2 = umaxu(P2, w1);
        }
      }
      __syncthreads();
      buf ^= 1;
    }
  }

  // ---- block merge: per row 4 slots x 2 -> top-4 -> global candP
  {
    const int mrow = rh * 32 + l31;
    const int slot = ch * 2 + lhi;
    mbuf[mrow * 8 + slot * 2 + 0] = P1;
    mbuf[mrow * 8 + slot * 2 + 1] = P2;
  }
  __syncthreads();
  if (tid < 64) {
    unsigned T1 = 0u, T2 = 0u, T3 = 0u, T4 = 0u;
#pragma unroll
    for (int j = 0; j < 8; ++j) {
      const unsigned p = mbuf[tid * 8 + j];
      const unsigned w1 = uminu(T1, p); T1 = umaxu(T1, p);
      const unsigned w2 = uminu(T2, w1); T2 = umaxu(T2, w1);
      const unsigned w3 = uminu(T3, w2); T3 = umaxu(T3, w2);
      T4 = umaxu(T4, w3);
    }
    const size_t o = (size_t)(row0 + tid) * 64 + bc * 4;
    candP[o + 0] = T1; candP[o + 1] = T2; candP[o + 2] = T3; candP[o + 3] = T4;
  }
}

// ---------------------------------------------------------------------------
// k_finalize: one block per row. FIRST zeroes its own row's alpha tail
// (cols [12288,16384), 16KB) — the __syncthreads chain (vmcnt(0) drain)
// orders these stores before the scatter. Then: top-8 of 64 packed cands,
// exact fp32 rescore, top-2 -> softmax -> scatter + emb mix * betaArr[row].
// (beta precomputed in prep; ph no longer read here.)
// ---------------------------------------------------------------------------
__global__ __launch_bounds__(256)
void k_finalize(const float* __restrict__ q, const float* __restrict__ keys,
                const float* __restrict__ embs, const float* __restrict__ betaArr,
                const unsigned* __restrict__ candP,
                float* __restrict__ outEmb, float* __restrict__ outAlpha) {
  __shared__ int   topIdx[8];
  __shared__ float resc[8];
  __shared__ float sParam[2];  // a1, a2
  __shared__ int   sIdx[2];
  const int tid = threadIdx.x;
  const int wave = tid >> 6, lane = tid & 63;
  const int row = blockIdx.x;
  float* arow = outAlpha + (size_t)row * N_;

  // Phase A: zero own-row tail: f4 [3072, 4096)
  {
    float4* a4 = reinterpret_cast<float4*>(arow);
    const float4 z4 = {0.f, 0.f, 0.f, 0.f};
#pragma unroll
    for (int i = 0; i < 4; ++i) a4[3072 + i * 256 + tid] = z4;
  }

  // Phase C (wave 0): top-8 of 64 packed candidates by repeated wave-max.
  if (wave == 0) {
    unsigned p = candP[(size_t)row * 64 + lane];
    const int mycol = (lane >> 2) * 1024 + (int)(p & 0x7FFu);
#pragma unroll
    for (int it = 0; it < 8; ++it) {
      unsigned mx = p;
#pragma unroll
      for (int m = 32; m >= 1; m >>= 1) {
        const unsigned o = (unsigned)__shfl_xor((int)mx, m);
        mx = mx > o ? mx : o;
      }
      const unsigned long long bal = __ballot(p == mx);
      const int src = __ffsll((unsigned long long)bal) - 1;
      if (lane == src) { topIdx[it] = mycol; p = 0u; }
    }
  }
  __syncthreads();

  // Phase D: exact fp32 rescore of the 8 candidates; wave w does 2.
  {
#pragma unroll
    for (int h = 0; h < 2; ++h) {
      const int cnd = topIdx[wave * 2 + h];
      const float4 qv = *reinterpret_cast<const float4*>(&q[(size_t)row * KD + lane * 4]);
      const float4 kv = *reinterpret_cast<const float4*>(&keys[(size_t)cnd * KD + lane * 4]);
      float s = qv.x * kv.x + qv.y * kv.y + qv.z * kv.z + qv.w * kv.w;
#pragma unroll
      for (int m = 32; m >= 1; m >>= 1) s += __shfl_xor(s, m);
      if (lane == 0) resc[wave * 2 + h] = s * 0.0625f;
    }
  }
  __syncthreads();

  // Phase E (thread 0): top-2 of rescored (tie -> lower index), softmax.
  if (tid == 0) {
    float w1 = -INFINITY, w2 = -INFINITY; int j1 = 0x7fffffff, j2 = 0x7fffffff;
#pragma unroll
    for (int c = 0; c < 8; ++c) {
      const float v = resc[c]; const int x = topIdx[c];
      const bool beat1 = (v > w1) || (v == w1 && x < j1);
      const bool beat2 = (v > w2) || (v == w2 && x < j2);
      if (beat1) { w2 = w1; j2 = j1; w1 = v; j1 = x; }
      else if (beat2) { w2 = v; j2 = x; }
    }
    const float t = expf(w2 - w1);
    const float inv = 1.f / (1.f + t);
    sParam[0] = inv; sParam[1] = t * inv;
    sIdx[0] = j1; sIdx[1] = j2;
  }
  __syncthreads();   // drains Phase A tail-zero stores too -> scatter is safe

  // Phase F: scatter alpha and emb mix.
  const float a1 = sParam[0], a2 = sParam[1];
  const float beta = betaArr[row];
  const int j1 = sIdx[0], j2 = sIdx[1];
  if (tid == 0) { arow[j1] = a1; arow[j2] = a2; }
  if (tid < 128) {
    const int f = tid * 4;
    const float4 e1 = *reinterpret_cast<const float4*>(&embs[(size_t)j1 * F_ + f]);
    const float4 e2 = *reinterpret_cast<const float4*>(&embs[(size_t)j2 * F_ + f]);
    float4 o;
    o.x = beta * (a1 * e1.x + a2 * e2.x);
    o.y = beta * (a1 * e1.y + a2 * e2.y);
    o.z = beta * (a1 * e1.z + a2 * e2.z);
    o.w = beta * (a1 * e1.w + a2 * e2.w);
    *reinterpret_cast<float4*>(&outEmb[(size_t)row * F_ + f]) = o;
  }
}

// ---------------------------------------------------------------------------
extern "C" void kernel_launch(void* const* d_in, const int* in_sizes, int n_in,
                              void* d_out, int out_size, void* d_ws, size_t ws_size,
                              hipStream_t stream) {
  const float* ph   = (const float*)d_in[0];
  const float* keys = (const float*)d_in[1];
  const float* embs = (const float*)d_in[2];
  const float* Wq   = (const float*)d_in[3];
  const float* bq   = (const float*)d_in[4];
  const float* Wb   = (const float*)d_in[5];
  const float* bb   = (const float*)d_in[6];

  float* outEmb   = (float*)d_out;
  float* outAlpha = outEmb + (size_t)B_ * F_;

  // workspace (~16 MB)
  float*          q       = (float*)d_ws;                                 // 4 MB
  unsigned short* qbf     = (unsigned short*)(q + (size_t)B_ * KD);       // 2 MB
  unsigned short* kbf     = qbf + (size_t)B_ * KD;                        // 8 MB
  unsigned*       candP   = (unsigned*)(kbf + (size_t)N_ * KD);           // 1 MB
  unsigned short* wqT_hi  = (unsigned short*)(candP + (size_t)B_ * 64);   // 0.5 MB
  unsigned short* wqT_lo  = wqT_hi + (size_t)KD * Q_;                     // 0.5 MB
  float*          betaArr = (float*)(wqT_lo + (size_t)KD * Q_);           // 16 KB

  k_prep<<<1088, 256, 0, stream>>>(Wq, wqT_hi, wqT_lo, ph, Wb, bb, betaArr);
  k_qproj_mfma<<<2560, 256, 0, stream>>>(ph, wqT_hi, wqT_lo, bq, q, qbf,
                                         keys, kbf);
  k_scores_mfma<<<dim3(16, 64), 256, 0, stream>>>(qbf, kbf, candP, outAlpha);
  k_finalize<<<B_, 256, 0, stream>>>(q, keys, embs, betaArr, candP,
                                     outEmb, outAlpha);
}